// Round 13
// baseline (140.358 us; speedup 1.0000x reference)
//
#include <hip/hip_runtime.h>
#include <math.h>

#define NB 4
#define NL 2048
#define ND 768
#define NH 12
#define NK 9
#define NIPG 64
#define NPAD 4
#define LT 16
#define NGEMM 384     // gemm blocks in fused launch (64 m-panels x 6 n)

typedef __attribute__((ext_vector_type(8))) short s16x8;
typedef __attribute__((ext_vector_type(4))) float f32x4;

__device__ __forceinline__ unsigned short f2bf(float f) {
  unsigned int u = __float_as_uint(f);
  unsigned int r = (u + 0x7FFFu + ((u >> 16) & 1u)) >> 16;
  return (unsigned short)r;
}
__device__ __forceinline__ float bf2f(unsigned short s) {
  return __uint_as_float(((unsigned int)s) << 16);
}
__device__ __forceinline__ void gload16(const void* g, void* l) {
  __builtin_amdgcn_global_load_lds((const __attribute__((address_space(1))) void*)g,
                                   (__attribute__((address_space(3))) void*)l,
                                   16, 0, 0);
}

// ---------------------------------------------------------------------------
// Kernel 0: prep — q -> qb (bf16, grid-stride), pt_w -> ptb, pw_w -> pwb,
// ak_w -> akp (k-padded to 16).  Unchanged from r12.
// ---------------------------------------------------------------------------
__global__ __launch_bounds__(256) void prep(const float* __restrict__ q,
                                            const float* __restrict__ pt_w,
                                            const float* __restrict__ pw_w,
                                            const float* __restrict__ ak_w,
                                            unsigned short* __restrict__ qb,
                                            unsigned short* __restrict__ ptb,
                                            unsigned short* __restrict__ pwb,
                                            unsigned short* __restrict__ akp) {
  const int t = blockIdx.x * 256 + threadIdx.x;
  for (int i = t; i < NB * NL * ND / 4; i += gridDim.x * 256) {
    float4 f = ((const float4*)q)[i];
    ushort4 o; o.x = f2bf(f.x); o.y = f2bf(f.y); o.z = f2bf(f.z); o.w = f2bf(f.w);
    ((ushort4*)qb)[i] = o;
  }
  if (t < ND * ND / 4) {
    float4 f = ((const float4*)pt_w)[t];
    ushort4 o; o.x = f2bf(f.x); o.y = f2bf(f.y); o.z = f2bf(f.z); o.w = f2bf(f.w);
    ((ushort4*)ptb)[t] = o;
  }
  if (t < NH * NIPG * NIPG / 4) {
    float4 f = ((const float4*)pw_w)[t];
    ushort4 o; o.x = f2bf(f.x); o.y = f2bf(f.y); o.z = f2bf(f.z); o.w = f2bf(f.w);
    ((ushort4*)pwb)[t] = o;
  }
  if (t < NH * 16 * NIPG) {
    const int h = t >> 10;
    const int r = t & 1023;
    const int k = r >> 6;
    const int i = r & 63;
    akp[t] = (k < NK) ? f2bf(ak_w[((size_t)h * NK + k) * NIPG + i]) : (unsigned short)0;
  }
}

// ---------------------------------------------------------------------------
// Kernel 1: FUSED.  blockIdx < NGEMM: 128x128 v-GEMM block (r2-proven
// quadrant layout + r12 counted-vmcnt: 8 ds_read feed 16 MFMAs per K-step).
// blockIdx >= NGEMM: attn block doing TWO (l0,h,b) units (pairs share h,b).
// 1152 total blocks (~4.5/CU) -> single residency round, no tail.
// ---------------------------------------------------------------------------
__global__ __launch_bounds__(256) void fused(const unsigned short* __restrict__ qb,
                                             const unsigned short* __restrict__ ptb,
                                             const float* __restrict__ bias,
                                             unsigned short* __restrict__ v,
                                             const float* __restrict__ dw_w,
                                             const unsigned short* __restrict__ pwb,
                                             const float* __restrict__ pw_b,
                                             const unsigned short* __restrict__ akp,
                                             const float* __restrict__ ak_b,
                                             float* __restrict__ wout) {
  __shared__ unsigned char smem[32768];
  const int t = threadIdx.x;
  const int lane = t & 63;
  const int wv = t >> 6;
  const int fr = lane & 15;
  const int fq = lane >> 4;

  if (blockIdx.x < NGEMM) {
    // ========== GEMM branch: v = qb . ptb^T + bias  (128x128 tile) ==========
    const int g = blockIdx.x;
    const int xcd = g & 7;
    const int j = g >> 3;                 // 0..47
    const long mo = (long)(xcd * 8 + j / 6) * 128;   // 8 m-panels per XCD
    const int n0 = (j % 6) * 128;
    const int wr = wv >> 1, wc = wv & 1;  // wave -> 64x64 quadrant

    const int soff = t * 16;
    const int sr = soff >> 6;
    const int scb = soff & 63;
    const unsigned char* gA0 = (const unsigned char*)qb + (mo + sr) * 1536L + scb;
    const unsigned char* gA1 = gA0 + 64L * 1536;
    const unsigned char* gB0 = (const unsigned char*)ptb + (size_t)(n0 + sr) * 1536 + scb;
    const unsigned char* gB1 = gB0 + 64L * 1536;

    int aoff[4], boff[4];
#pragma unroll
    for (int m = 0; m < 4; ++m)
      aoff[m] = ((wr * 64 + m * 16 + fr) * 32 + fq * 8) * 2;
#pragma unroll
    for (int n = 0; n < 4; ++n)
      boff[n] = 8192 + ((wc * 64 + n * 16 + fr) * 32 + fq * 8) * 2;

#define STAGE(kt_)                                                 \
    do {                                                           \
      const long kb_ = (long)(kt_) * 64;                           \
      unsigned char* base_ = &smem[((kt_) & 1) * 16384];           \
      gload16(gA0 + kb_, base_ + soff);                            \
      gload16(gA1 + kb_, base_ + 4096 + soff);                     \
      gload16(gB0 + kb_, base_ + 8192 + soff);                     \
      gload16(gB1 + kb_, base_ + 12288 + soff);                    \
    } while (0)

#define FRAGS(kt_)                                                 \
    do {                                                           \
      const unsigned char* bb_ = &smem[((kt_) & 1) * 16384];       \
      _Pragma("unroll")                                            \
      for (int m_ = 0; m_ < 4; ++m_) av[m_] = *(const s16x8*)&bb_[aoff[m_]]; \
      _Pragma("unroll")                                            \
      for (int n_ = 0; n_ < 4; ++n_) bv[n_] = *(const s16x8*)&bb_[boff[n_]]; \
    } while (0)

#define MM16                                                       \
    do {                                                           \
      _Pragma("unroll")                                            \
      for (int m_ = 0; m_ < 4; ++m_)                               \
        _Pragma("unroll")                                          \
        for (int n_ = 0; n_ < 4; ++n_)                             \
          acc[m_][n_] = __builtin_amdgcn_mfma_f32_16x16x32_bf16(   \
              av[m_], bv[n_], acc[m_][n_], 0, 0, 0);               \
    } while (0)

    f32x4 acc[4][4] = {};
    s16x8 av[4], bv[4];

    STAGE(0);
    STAGE(1);                              // 8 loads in flight
    for (int kt = 0; kt < 23; ++kt) {
      asm volatile("s_waitcnt vmcnt(4)" ::: "memory");  // oldest tile's 4 done
      __builtin_amdgcn_s_barrier();                     // tile kt visible
      FRAGS(kt);
      asm volatile("s_waitcnt lgkmcnt(0)" ::: "memory");
      __builtin_amdgcn_sched_barrier(0);
      __builtin_amdgcn_s_barrier();                     // all reads of buf kt done
      if (kt + 2 < 24) STAGE(kt + 2);
      MM16;
    }
    {  // kt = 23
      asm volatile("s_waitcnt vmcnt(0)" ::: "memory");
      __builtin_amdgcn_s_barrier();
      FRAGS(23);
      MM16;
    }
#undef STAGE
#undef FRAGS
#undef MM16

    // epilogue: v bf16 (+bias).  C/D: col=lane&15, row=(lane>>4)*4+j
#pragma unroll
    for (int m = 0; m < 4; ++m) {
#pragma unroll
      for (int n = 0; n < 4; ++n) {
        const long row = mo + wr * 64 + m * 16 + fq * 4;
        const int col = n0 + wc * 64 + n * 16 + fr;
        const float bbv = bias[col];
#pragma unroll
        for (int jj = 0; jj < 4; ++jj)
          v[(row + jj) * ND + col] = f2bf(acc[m][n][jj] + bbv);
      }
    }
  } else {
    // ========== ATTN branch: two (l0) units, shared h,b ==========
    const int a2 = blockIdx.x - NGEMM;       // 0..767
    const int idx0 = a2 * 2;
    const int h  = (idx0 >> 5) % NH;
    const int b  = idx0 / (32 * NH);
    const int d0 = h * NIPG;

    unsigned short (*qs)[68] = (unsigned short(*)[68])smem;   // 72x68 bf16
    unsigned char* ab = smem + 9792;                          // 8KB swizzled

    // per-head constants hoisted across both units
    const unsigned short* pwh = pwb + (size_t)h * NIPG * NIPG;
    const unsigned short* akh = akp + (size_t)h * 16 * NIPG;
    s16x8 pv0[4], pv1[4];
#pragma unroll
    for (int n = 0; n < 4; ++n) {
      const int o = n * 16 + fr;
      pv0[n] = *(const s16x8*)&pwh[o * 64 + fq * 8];
      pv1[n] = *(const s16x8*)&pwh[o * 64 + 32 + fq * 8];
    }
    s16x8 ak0 = *(const s16x8*)&akh[fr * 64 + fq * 8];
    s16x8 ak1 = *(const s16x8*)&akh[fr * 64 + 32 + fq * 8];
    float dwk[NK];
#pragma unroll
    for (int k = 0; k < NK; ++k) dwk[k] = dw_w[(size_t)(d0 + lane) * NK + k];
    const bool kvalid = fr < NK;
    const float akbv = kvalid ? ak_b[h * NK + fr] : 0.f;
    const int lset = wv * 16;

    for (int u = 0; u < 2; ++u) {
      const int l0 = ((idx0 + u) & 31) * 64;
      if (u > 0) __syncthreads();        // prior unit's qs reads done

      {
        const int sl = t >> 4;
        const int sc = (t & 15) * 4;
        for (int r = sl; r < 72; r += 16) {
          const int l = l0 - NPAD + r;
          ushort4 ub = make_ushort4(0, 0, 0, 0);
          if (l >= 0 && l < NL)
            ub = *(const ushort4*)&qb[((size_t)(b * NL + l)) * ND + d0 + sc];
          *(ushort4*)&qs[r][sc] = ub;
        }
      }
      __syncthreads();

      {
        float win9[NK];
#pragma unroll
        for (int k = 0; k < NK; ++k) win9[k] = bf2f(qs[lset + k][lane]);
#pragma unroll
        for (int l2 = 0; l2 < 16; ++l2) {
          const int l = lset + l2;
          float s = 0.f;
#pragma unroll
          for (int k = 0; k < NK; ++k) s = fmaf(win9[k], dwk[k], s);
          const int byte = ((l * 64 + lane) * 2) ^ ((l & 7) << 4);
          *(unsigned short*)&ab[byte] = f2bf(s);
          if (l2 < 15) {
#pragma unroll
            for (int k = 0; k < NK - 1; ++k) win9[k] = win9[k + 1];
            win9[NK - 1] = bf2f(qs[lset + l2 + NK][lane]);
          }
        }
      }

      s16x8 av0, av1;
      {
        const int row = lset + fr;
        const int b0 = ((row * 64 + fq * 8) * 2)      ^ ((row & 7) << 4);
        const int b1 = ((row * 64 + 32 + fq * 8) * 2) ^ ((row & 7) << 4);
        av0 = *(const s16x8*)&ab[b0];
        av1 = *(const s16x8*)&ab[b1];
      }
      f32x4 accp[4];
#pragma unroll
      for (int n = 0; n < 4; ++n) {
        accp[n] = (f32x4){0.f, 0.f, 0.f, 0.f};
        accp[n] = __builtin_amdgcn_mfma_f32_16x16x32_bf16(av0, pv0[n], accp[n], 0, 0, 0);
        accp[n] = __builtin_amdgcn_mfma_f32_16x16x32_bf16(av1, pv1[n], accp[n], 0, 0, 0);
      }

#pragma unroll
      for (int n = 0; n < 4; ++n) {
        const int o = n * 16 + fr;
        const float pb = pw_b[d0 + o];
#pragma unroll
        for (int jj = 0; jj < 4; ++jj) {
          const int row = lset + fq * 4 + jj;
          const float ca = (accp[n][jj] + pb) * bf2f(qs[row + NPAD][o]);
          const int byte = ((row * 64 + o) * 2) ^ ((row & 7) << 4);
          *(unsigned short*)&ab[byte] = f2bf(ca);
        }
      }

      f32x4 acck = (f32x4){0.f, 0.f, 0.f, 0.f};
      {
        const int row = lset + fr;
        const int b0 = ((row * 64 + fq * 8) * 2)      ^ ((row & 7) << 4);
        const int b1 = ((row * 64 + 32 + fq * 8) * 2) ^ ((row & 7) << 4);
        s16x8 a0 = *(const s16x8*)&ab[b0];
        s16x8 a1 = *(const s16x8*)&ab[b1];
        acck = __builtin_amdgcn_mfma_f32_16x16x32_bf16(a0, ak0, acck, 0, 0, 0);
        acck = __builtin_amdgcn_mfma_f32_16x16x32_bf16(a1, ak1, acck, 0, 0, 0);
      }

#pragma unroll
      for (int jj = 0; jj < 4; ++jj) {
        float val = acck[jj] + akbv;
        float mv = kvalid ? val : -3.4e38f;
#pragma unroll
        for (int mm = 1; mm < 16; mm <<= 1) mv = fmaxf(mv, __shfl_xor(mv, mm));
        const float e = kvalid ? __expf(val - mv) : 0.f;
        float ssum = e;
#pragma unroll
        for (int mm = 1; mm < 16; mm <<= 1) ssum += __shfl_xor(ssum, mm);
        if (kvalid) {
          const int row = l0 + lset + fq * 4 + jj;
          wout[(((size_t)(b * NL + row)) * NH + h) * NK + fr] = e / ssum;
        }
      }
    }
  }
}

// ---------------------------------------------------------------------------
// Kernel 2: out[b,l,d] = sum_k w[b,l,h,k] * v[b,l+k-4,d]  (r3-proven rolling
// window; v bf16).  Unchanged.
// ---------------------------------------------------------------------------
__global__ __launch_bounds__(192) void sdconv_out(const unsigned short* __restrict__ v,
                                                  const float* __restrict__ w,
                                                  float* __restrict__ out) {
  const int b  = blockIdx.y;
  const int l0 = blockIdx.x * LT;
  const int t  = threadIdx.x;          // 0..191
  const int d  = t * 4;
  const int h  = t >> 4;
  const size_t vbase = (size_t)b * NL * ND + d;

  float4 win[NK];
#pragma unroll
  for (int k = 0; k < NK; ++k) {
    const int r = l0 - NPAD + k;
    if (r >= 0 && r < NL) {
      ushort4 u = *(const ushort4*)&v[vbase + (size_t)r * ND];
      win[k] = make_float4(bf2f(u.x), bf2f(u.y), bf2f(u.z), bf2f(u.w));
    } else {
      win[k] = make_float4(0.f, 0.f, 0.f, 0.f);
    }
  }
#pragma unroll
  for (int l2 = 0; l2 < LT; ++l2) {
    const int l = l0 + l2;
    const float* wp = &w[(((size_t)(b * NL + l)) * NH + h) * NK];
    float4 acc = make_float4(0.f, 0.f, 0.f, 0.f);
#pragma unroll
    for (int k = 0; k < NK; ++k) {
      const float wk = wp[k];
      acc.x = fmaf(wk, win[k].x, acc.x);
      acc.y = fmaf(wk, win[k].y, acc.y);
      acc.z = fmaf(wk, win[k].z, acc.z);
      acc.w = fmaf(wk, win[k].w, acc.w);
    }
    *(float4*)&out[(size_t)(b * NL + l) * ND + d] = acc;
#pragma unroll
    for (int k = 0; k < NK - 1; ++k) win[k] = win[k + 1];
    const int rn = l + NPAD + 1;
    if (rn < NL) {
      ushort4 u = *(const ushort4*)&v[vbase + (size_t)rn * ND];
      win[NK - 1] = make_float4(bf2f(u.x), bf2f(u.y), bf2f(u.z), bf2f(u.w));
    } else {
      win[NK - 1] = make_float4(0.f, 0.f, 0.f, 0.f);
    }
  }
}

// ---------------------------------------------------------------------------
extern "C" void kernel_launch(void* const* d_in, const int* in_sizes, int n_in,
                              void* d_out, int out_size, void* d_ws, size_t ws_size,
                              hipStream_t stream) {
  const float* query = (const float*)d_in[0];
  const float* dw_w  = (const float*)d_in[1];
  const float* pw_w  = (const float*)d_in[2];
  const float* pw_b  = (const float*)d_in[3];
  const float* ak_w  = (const float*)d_in[4];
  const float* ak_b  = (const float*)d_in[5];
  const float* pt_w  = (const float*)d_in[6];
  const float* pt_b  = (const float*)d_in[7];
  float* out = (float*)d_out;

  // workspace layout (~30.5 MB of 268 MB)
  float* w = (float*)d_ws;                                        // 3.54MB
  unsigned short* qb  = (unsigned short*)(w + (size_t)NB * NL * NH * NK); // 12.6MB
  unsigned short* ptb = qb + (size_t)NB * NL * ND;                // 1.18MB
  unsigned short* pwb = ptb + (size_t)ND * ND;                    // 98KB
  unsigned short* akp = pwb + (size_t)NH * NIPG * NIPG;           // 24.6KB
  unsigned short* v   = akp + (size_t)NH * 16 * NIPG;             // 12.6MB bf16

  prep<<<2048, 256, 0, stream>>>(query, pt_w, pw_w, ak_w, qb, ptb, pwb, akp);

  fused<<<NGEMM + 32 * NH * NB / 2, 256, 0, stream>>>(qb, ptb, pt_b, v,
                                                      dw_w, pwb, pw_b, akp, ak_b, w);

  dim3 g3(NL / LT, NB, 1);
  sdconv_out<<<g3, 192, 0, stream>>>(v, w, out);
}